// Round 1
// baseline (506.970 us; speedup 1.0000x reference)
//
#include <hip/hip_runtime.h>
#include <hip/hip_bf16.h>
#include <stdint.h>

// Problem constants
#define DIMN   2048
#define L_SEQ  2048
#define BATCH  2
#define NHEADS 16
#define NKVH   4
#define HDIM   128
#define MROWS  (BATCH * L_SEQ)        // 4096
#define NQKV   (DIMN + 2 * NKVH * HDIM) // 3072

typedef unsigned short u16;
typedef __bf16 bf16_t;
typedef bf16_t bf16x8 __attribute__((ext_vector_type(8)));
typedef float  f32x4  __attribute__((ext_vector_type(4)));
typedef u16    u16x8  __attribute__((ext_vector_type(8)));

__device__ __forceinline__ u16 f2bf(float f) {
  union { float f; uint32_t u; } v; v.f = f;
  uint32_t r = v.u + 0x7fffu + ((v.u >> 16) & 1u);   // RNE
  return (u16)(r >> 16);
}

// async global->LDS, 16B per lane; LDS base must be wave-uniform (dest = base + lane*16)
#define GLOAD_LDS16(gp, lp)                                                     \
  __builtin_amdgcn_global_load_lds(                                             \
      (const __attribute__((address_space(1))) void*)(gp),                      \
      (__attribute__((address_space(3))) void*)(lp), 16, 0, 0)

// ---------------------------------------------------------------- convert
__global__ void conv_f32_bf16(const float* __restrict__ src,
                              u16* __restrict__ dst, int n4) {
  int i = blockIdx.x * blockDim.x + threadIdx.x;
  int stride = gridDim.x * blockDim.x;
  for (; i < n4; i += stride) {
    float4 v = ((const float4*)src)[i];
    ushort4 o;
    o.x = f2bf(v.x); o.y = f2bf(v.y); o.z = f2bf(v.z); o.w = f2bf(v.w);
    ((ushort4*)dst)[i] = o;
  }
}

// ---------------------------------------------------------------- GEMM (m97 structure)
// C[M,N] (f32, row-major) = A[M,K] (bf16 rm) * B[N,K]^T (bf16 rm).
// 128x128 tile, BK=64, 4 waves (2x2), each wave 64x64 = 4x4 frags of 16x16x32.
__global__ __launch_bounds__(256) void gemm_bf16_bt(
    const u16* __restrict__ A, const u16* __restrict__ B,
    float* __restrict__ C, int M, int N, int K) {
  __shared__ u16 As[128 * 64];
  __shared__ u16 Bs[128 * 64];
  const int tid  = threadIdx.x;
  const int lane = tid & 63;
  const int wid  = tid >> 6;
  const int l15  = lane & 15, l4 = lane >> 4;
  const int bm = blockIdx.y, bn = blockIdx.x;
  const int wr = wid >> 1, wc = wid & 1;

  f32x4 acc[4][4] = {};

  for (int k0 = 0; k0 < K; k0 += 64) {
    // stage A,B tiles: 1024 chunks of 16B each, linear LDS
#pragma unroll
    for (int is = 0; is < 4; ++is) {
      int cc = is * 256 + tid;           // == is*256 + wid*64 + lane
      int rr = cc >> 3, c = (cc & 7) << 3;
      GLOAD_LDS16(A + (size_t)(bm * 128 + rr) * K + k0 + c,
                  &As[(is * 256 + wid * 64) * 8]);
      GLOAD_LDS16(B + (size_t)(bn * 128 + rr) * K + k0 + c,
                  &Bs[(is * 256 + wid * 64) * 8]);
    }
    __syncthreads();   // waits vmcnt(0) per compiler barrier semantics

#pragma unroll
    for (int kk = 0; kk < 2; ++kk) {
      const int ko = kk * 32 + l4 * 8;
      bf16x8 af[4], bfr[4];
#pragma unroll
      for (int m = 0; m < 4; ++m)
        af[m] = *(const bf16x8*)&As[(wr * 64 + m * 16 + l15) * 64 + ko];
#pragma unroll
      for (int n = 0; n < 4; ++n)
        bfr[n] = *(const bf16x8*)&Bs[(wc * 64 + n * 16 + l15) * 64 + ko];
#pragma unroll
      for (int m = 0; m < 4; ++m)
#pragma unroll
        for (int n = 0; n < 4; ++n)
          acc[m][n] = __builtin_amdgcn_mfma_f32_16x16x32_bf16(
              af[m], bfr[n], acc[m][n], 0, 0, 0);
    }
    __syncthreads();
  }

  // epilogue: C/D layout col=lane&15, row=(lane>>4)*4+j  [m89 verified]
  const int crow0 = bm * 128 + wr * 64;
  const int ccol0 = bn * 128 + wc * 64;
#pragma unroll
  for (int m = 0; m < 4; ++m)
#pragma unroll
    for (int n = 0; n < 4; ++n)
#pragma unroll
      for (int j = 0; j < 4; ++j)
        C[(size_t)(crow0 + m * 16 + l4 * 4 + j) * N + ccol0 + n * 16 + l15] =
            acc[m][n][j];
}

// ---------------------------------------------------------------- RMSNorm + RoPE + scatter
// qkv rows: [0..2048) q (16 heads x128), [2048..2560) k, [2560..3072) v.
// One wave per (token-row, head-slot); lane i owns rope pair (2i, 2i+1).
__global__ __launch_bounds__(256) void rms_rope(
    const float* __restrict__ qkv, const float* __restrict__ qg,
    const float* __restrict__ kg, u16* __restrict__ qb,
    u16* __restrict__ kb, u16* __restrict__ vb) {
  const int gw   = blockIdx.x * 4 + (threadIdx.x >> 6);
  const int lane = threadIdx.x & 63;
  const int row  = gw / 24;            // 0..4095
  const int slot = gw % 24;            // 0..15 q, 16..19 k, 20..23 v
  const int b = row >> 11, pos = row & 2047;

  int colbase = (slot < 16) ? slot * 128
              : (slot < 20) ? 2048 + (slot - 16) * 128
                            : 2560 + (slot - 20) * 128;
  const float* src = qkv + (size_t)row * NQKV + colbase;
  float2 v = *(const float2*)(src + 2 * lane);
  float re = v.x, im = v.y;

  if (slot < 20) {   // rmsnorm + rope for q,k
    float ss = re * re + im * im;
#pragma unroll
    for (int m = 1; m < 64; m <<= 1) ss += __shfl_xor(ss, m, 64);
    float inv = rsqrtf(ss * (1.0f / 128.0f) + 1e-6f);
    const float* gamma = (slot < 16) ? qg : kg;
    re = re * inv * gamma[2 * lane];
    im = im * inv * gamma[2 * lane + 1];
    float freq = powf(10000.0f, -(float)lane / 64.0f);
    float ang = (float)pos * freq;
    float s, c;
    sincosf(ang, &s, &c);
    float ore = re * c - im * s;
    float oim = re * s + im * c;
    re = ore; im = oim;
  }

  ushort2 o; o.x = f2bf(re); o.y = f2bf(im);
  u16* dst;
  if (slot < 16)
    dst = qb + ((size_t)((b * NHEADS + slot) * L_SEQ) + pos) * HDIM + 2 * lane;
  else if (slot < 20)
    dst = kb + ((size_t)((b * NKVH + slot - 16) * L_SEQ) + pos) * HDIM + 2 * lane;
  else
    dst = vb + ((size_t)((b * NKVH + slot - 20) * L_SEQ) + pos) * HDIM + 2 * lane;
  *(ushort2*)dst = o;
}

// ---------------------------------------------------------------- flash attention
// Block: 4 waves, 64 q-rows (16/wave), KVBLK=64, D=128. Online softmax in regs.
__global__ __launch_bounds__(256) void attn_kernel(
    const u16* __restrict__ qb, const u16* __restrict__ kb,
    const u16* __restrict__ vb, const int* __restrict__ mask,
    u16* __restrict__ ob) {
  __shared__ u16 Ks[64 * 128];   // logical [k][d], dchunks XOR-swizzled per row
  __shared__ u16 Vt[128 * 64];   // logical [d][k] (V transposed), XOR-swizzled
  __shared__ u16 Ps[64 * 64];    // P roundtrip, XOR-swizzled, per-wave private rows

  const int qt = blockIdx.x;           // q tile (64 rows)
  const int bh = blockIdx.y;           // b*16 + h
  const int b = bh >> 4, h = bh & 15, kvh = h >> 2;
  const int tid = threadIdx.x;
  const int lane = tid & 63, wid = tid >> 6;
  const int l15 = lane & 15, l4 = lane >> 4;

  const u16* Q  = qb + ((size_t)((b * NHEADS + h) * L_SEQ) + qt * 64) * HDIM;
  const u16* Kg = kb + (size_t)((b * NKVH + kvh) * L_SEQ) * HDIM;
  const u16* Vg = vb + (size_t)((b * NKVH + kvh) * L_SEQ) * HDIM;
  const int* msk = mask + b * L_SEQ;

  // Q fragments live in registers for the whole kernel
  bf16x8 qf[4];
  {
    const u16* qrow = Q + (wid * 16 + l15) * HDIM + l4 * 8;
#pragma unroll
    for (int kk = 0; kk < 4; ++kk) qf[kk] = *(const bf16x8*)(qrow + kk * 32);
  }

  f32x4 o[8] = {};
  float mst[4] = {-1e30f, -1e30f, -1e30f, -1e30f};
  float lst[4] = {0.f, 0.f, 0.f, 0.f};
  const float SCALE = 0.08838834764831845f;   // 1/sqrt(128)

  for (int t = 0; t < L_SEQ / 64; ++t) {
    const int kv0 = t * 64;

    // stage K: linear LDS dest + inverse-swizzled global source (m173 pattern)
#pragma unroll
    for (int is = 0; is < 4; ++is) {
      int cc = is * 256 + tid;
      int kr = cc >> 4, pos = cc & 15;
      int dch = pos ^ (kr & 7);
      GLOAD_LDS16(Kg + (size_t)(kv0 + kr) * HDIM + dch * 8,
                  &Ks[(is * 256 + wid * 64) * 8]);
    }
    // stage V transposed + swizzled via registers (ds_writes conflict-free: lanes span krow)
#pragma unroll
    for (int is = 0; is < 4; ++is) {
      int cc = is * 256 + tid;
      int kr = cc & 63, d0 = (cc >> 6) << 3;
      u16x8 vv = *(const u16x8*)(Vg + (size_t)(kv0 + kr) * HDIM + d0);
#pragma unroll
      for (int j = 0; j < 8; ++j)
        Vt[(d0 + j) * 64 + (kr ^ (j << 3))] = vv[j];
    }
    __syncthreads();

    // S = Q K^T  (wave's 16 q-rows x 64 k-cols)
    f32x4 s[4] = {};
#pragma unroll
    for (int kk = 0; kk < 4; ++kk) {
#pragma unroll
      for (int nf = 0; nf < 4; ++nf) {
        int kr = nf * 16 + l15;
        int dch = kk * 4 + l4;
        bf16x8 kf = *(const bf16x8*)&Ks[(kr * 16 + (dch ^ (kr & 7))) * 8];
        s[nf] = __builtin_amdgcn_mfma_f32_16x16x32_bf16(qf[kk], kf, s[nf], 0, 0, 0);
      }
    }

    // scale + mask bias
    float bias[4];
#pragma unroll
    for (int nf = 0; nf < 4; ++nf)
      bias[nf] = msk[kv0 + nf * 16 + l15] ? 0.0f : -1e30f;
    float sv[4][4];
#pragma unroll
    for (int nf = 0; nf < 4; ++nf)
#pragma unroll
      for (int j = 0; j < 4; ++j)
        sv[nf][j] = s[nf][j] * SCALE + bias[nf];

    // online softmax: rows live in 16-lane groups -> xor-reduce over low 4 bits
    float mnew[4], alpha[4], psum[4];
#pragma unroll
    for (int j = 0; j < 4; ++j) {
      float mv = fmaxf(fmaxf(sv[0][j], sv[1][j]), fmaxf(sv[2][j], sv[3][j]));
#pragma unroll
      for (int x = 1; x < 16; x <<= 1) mv = fmaxf(mv, __shfl_xor(mv, x, 64));
      mnew[j] = fmaxf(mst[j], mv);
      alpha[j] = __expf(mst[j] - mnew[j]);
      mst[j] = mnew[j];
      psum[j] = 0.f;
    }
    // P = exp(S - m), write to swizzled LDS (per-wave rows, no cross-wave barrier needed)
#pragma unroll
    for (int nf = 0; nf < 4; ++nf) {
      int col = nf * 16 + l15;
#pragma unroll
      for (int j = 0; j < 4; ++j) {
        int rl = wid * 16 + l4 * 4 + j;
        float p = __expf(sv[nf][j] - mnew[j]);
        psum[j] += p;
        Ps[rl * 64 + (col ^ ((rl & 7) << 3))] = f2bf(p);
      }
    }
#pragma unroll
    for (int j = 0; j < 4; ++j) {
      float ps = psum[j];
#pragma unroll
      for (int x = 1; x < 16; x <<= 1) ps += __shfl_xor(ps, x, 64);
      lst[j] = lst[j] * alpha[j] + ps;
    }
    // rescale O by alpha
#pragma unroll
    for (int df = 0; df < 8; ++df)
#pragma unroll
      for (int j = 0; j < 4; ++j) o[df][j] *= alpha[j];

    // PV: O += P @ V   (A=P[16q x 64k], B=Vt rows = output d)
#pragma unroll
    for (int kk = 0; kk < 2; ++kk) {
      int prow = wid * 16 + l15;
      int ec = kk * 4 + l4;
      bf16x8 pa = *(const bf16x8*)&Ps[prow * 64 + ((ec ^ (prow & 7)) * 8)];
#pragma unroll
      for (int df = 0; df < 8; ++df) {
        int d = df * 16 + l15;
        bf16x8 vf = *(const bf16x8*)&Vt[d * 64 + ((ec ^ (d & 7)) * 8)];
        o[df] = __builtin_amdgcn_mfma_f32_16x16x32_bf16(pa, vf, o[df], 0, 0, 0);
      }
    }
    __syncthreads();   // all waves done reading Ks/Vt before next stage
  }

  // epilogue: normalize and write bf16 in [B,L,H*D] layout for O-proj GEMM
  float rl[4];
#pragma unroll
  for (int j = 0; j < 4; ++j) rl[j] = 1.0f / lst[j];
#pragma unroll
  for (int df = 0; df < 8; ++df)
#pragma unroll
    for (int j = 0; j < 4; ++j) {
      int qrow = qt * 64 + wid * 16 + l4 * 4 + j;
      int col = h * HDIM + df * 16 + l15;
      ob[(size_t)(b * L_SEQ + qrow) * DIMN + col] = f2bf(o[df][j] * rl[j]);
    }
}

// ---------------------------------------------------------------- launch
extern "C" void kernel_launch(void* const* d_in, const int* in_sizes, int n_in,
                              void* d_out, int out_size, void* d_ws, size_t ws_size,
                              hipStream_t stream) {
  const float* x  = (const float*)d_in[0];
  const int* mask = (const int*)d_in[1];
  const float* Wq = (const float*)d_in[2];
  const float* Wk = (const float*)d_in[3];
  const float* Wv = (const float*)d_in[4];
  const float* Wo = (const float*)d_in[5];
  const float* qg = (const float*)d_in[6];
  const float* kg = (const float*)d_in[7];
  float* out = (float*)d_out;

  // workspace layout (bytes): total 113,246,208 needed
  char* ws = (char*)d_ws;
  u16*   xb   = (u16*)(ws + 0);           // 16 MB   [4096,2048] bf16
  u16*   wqkv = (u16*)(ws + 16777216);    // 12 MB   [3072,2048] bf16 (Wq|Wk|Wv)
  u16*   wob  = (u16*)(ws + 29360128);    //  8 MB   [2048,2048] bf16
  float* qkv  = (float*)(ws + 37748736);  // 48 MB   [4096,3072] f32
  u16*   qb   = (u16*)(ws + 88080384);    // 16 MB   [B,H,L,HD] bf16
  u16*   kb   = (u16*)(ws + 104857600);   //  4 MB   [B,KVH,L,HD]
  u16*   vb   = (u16*)(ws + 109051904);   //  4 MB
  u16*   ob   = (u16*)(ws + 37748736);    // 16 MB, aliases qkv (free after rms_rope)

  conv_f32_bf16<<<1024, 256, 0, stream>>>(x,  xb,   2097152);
  conv_f32_bf16<<<1024, 256, 0, stream>>>(Wq, wqkv, 1048576);
  conv_f32_bf16<<<512,  256, 0, stream>>>(Wk, wqkv + 4194304, 262144);
  conv_f32_bf16<<<512,  256, 0, stream>>>(Wv, wqkv + 5242880, 262144);
  conv_f32_bf16<<<1024, 256, 0, stream>>>(Wo, wob,  1048576);

  gemm_bf16_bt<<<dim3(NQKV / 128, MROWS / 128), 256, 0, stream>>>(
      xb, wqkv, qkv, MROWS, NQKV, DIMN);
  rms_rope<<<MROWS * 24 / 4, 256, 0, stream>>>(qkv, qg, kg, qb, kb, vb);
  attn_kernel<<<dim3(L_SEQ / 64, BATCH * NHEADS), 256, 0, stream>>>(
      qb, kb, vb, mask, ob);
  gemm_bf16_bt<<<dim3(DIMN / 128, MROWS / 128), 256, 0, stream>>>(
      ob, wob, out, MROWS, DIMN, DIMN);
}

// Round 8
// 372.521 us; speedup vs baseline: 1.3609x; 1.3609x over previous
//
#include <hip/hip_runtime.h>
#include <hip/hip_bf16.h>
#include <stdint.h>

// Problem constants
#define DIMN   2048
#define L_SEQ  2048
#define BATCH  2
#define NHEADS 16
#define NKVH   4
#define HDIM   128
#define MROWS  (BATCH * L_SEQ)          // 4096
#define NQKV   (DIMN + 2 * NKVH * HDIM) // 3072

typedef unsigned short u16;
typedef __bf16 bf16_t;
typedef bf16_t bf16x8 __attribute__((ext_vector_type(8)));
typedef float  f32x4  __attribute__((ext_vector_type(4)));
typedef float  f32x16 __attribute__((ext_vector_type(16)));
typedef u16    u16x8  __attribute__((ext_vector_type(8)));

__device__ __forceinline__ u16 f2bf(float f) {
  union { float f; uint32_t u; } v; v.f = f;
  uint32_t r = v.u + 0x7fffu + ((v.u >> 16) & 1u);   // RNE
  return (u16)(r >> 16);
}

// 2^x via v_exp_f32 (log2-domain softmax)
__device__ __forceinline__ float fexp2(float x) {
  float r; asm("v_exp_f32 %0, %1" : "=v"(r) : "v"(x)); return r;
}
// pack 2 f32 -> 1 u32 of 2 bf16 (lo=a, hi=b), RNE
__device__ __forceinline__ uint32_t cvtpk(float a, float b) {
  uint32_t r; asm("v_cvt_pk_bf16_f32 %0, %1, %2" : "=v"(r) : "v"(a), "v"(b)); return r;
}
// v_permlane32_swap_b32: a'[l>=32]=b[l-32], b'[l<32]=a[l+32]
__device__ __forceinline__ void plswap(uint32_t& a, uint32_t& b) {
  asm volatile("v_permlane32_swap_b32 %0, %1" : "+v"(a), "+v"(b));
}

// async global->LDS, 16B per lane; LDS dest = wave-uniform base + lane*16
#define GLOAD_LDS16(gp, lp)                                                     \
  __builtin_amdgcn_global_load_lds(                                             \
      (const __attribute__((address_space(1))) void*)(gp),                      \
      (__attribute__((address_space(3))) void*)(lp), 16, 0, 0)

// ---------------------------------------------------------------- convert
__global__ void conv_f32_bf16(const float* __restrict__ src,
                              u16* __restrict__ dst, int n4) {
  int i = blockIdx.x * blockDim.x + threadIdx.x;
  int stride = gridDim.x * blockDim.x;
  for (; i < n4; i += stride) {
    float4 v = ((const float4*)src)[i];
    ushort4 o;
    o.x = f2bf(v.x); o.y = f2bf(v.y); o.z = f2bf(v.z); o.w = f2bf(v.w);
    ((ushort4*)dst)[i] = o;
  }
}

// ---------------------------------------------------------------- GEMM (m97 structure)
// C[M,N] (f32, row-major) = A[M,K] (bf16 rm) * B[N,K]^T (bf16 rm).
__global__ __launch_bounds__(256) void gemm_bf16_bt(
    const u16* __restrict__ A, const u16* __restrict__ B,
    float* __restrict__ C, int M, int N, int K) {
  __shared__ u16 As[128 * 64];
  __shared__ u16 Bs[128 * 64];
  const int tid  = threadIdx.x;
  const int lane = tid & 63;
  const int wid  = tid >> 6;
  const int l15  = lane & 15, l4 = lane >> 4;
  const int bm = blockIdx.y, bn = blockIdx.x;
  const int wr = wid >> 1, wc = wid & 1;

  f32x4 acc[4][4] = {};

  for (int k0 = 0; k0 < K; k0 += 64) {
#pragma unroll
    for (int is = 0; is < 4; ++is) {
      int cc = is * 256 + tid;
      int rr = cc >> 3, c = (cc & 7) << 3;
      GLOAD_LDS16(A + (size_t)(bm * 128 + rr) * K + k0 + c,
                  &As[(is * 256 + wid * 64) * 8]);
      GLOAD_LDS16(B + (size_t)(bn * 128 + rr) * K + k0 + c,
                  &Bs[(is * 256 + wid * 64) * 8]);
    }
    __syncthreads();

#pragma unroll
    for (int kk = 0; kk < 2; ++kk) {
      const int ko = kk * 32 + l4 * 8;
      bf16x8 af[4], bfr[4];
#pragma unroll
      for (int m = 0; m < 4; ++m)
        af[m] = *(const bf16x8*)&As[(wr * 64 + m * 16 + l15) * 64 + ko];
#pragma unroll
      for (int n = 0; n < 4; ++n)
        bfr[n] = *(const bf16x8*)&Bs[(wc * 64 + n * 16 + l15) * 64 + ko];
#pragma unroll
      for (int m = 0; m < 4; ++m)
#pragma unroll
        for (int n = 0; n < 4; ++n)
          acc[m][n] = __builtin_amdgcn_mfma_f32_16x16x32_bf16(
              af[m], bfr[n], acc[m][n], 0, 0, 0);
    }
    __syncthreads();
  }

  const int crow0 = bm * 128 + wr * 64;
  const int ccol0 = bn * 128 + wc * 64;
#pragma unroll
  for (int m = 0; m < 4; ++m)
#pragma unroll
    for (int n = 0; n < 4; ++n)
#pragma unroll
      for (int j = 0; j < 4; ++j)
        C[(size_t)(crow0 + m * 16 + l4 * 4 + j) * N + ccol0 + n * 16 + l15] =
            acc[m][n][j];
}

// ---------------------------------------------------------------- RMSNorm + RoPE (q,k only)
// qkv rows: [0..2048) q (16 heads x128), [2048..2560) k. q prescaled by 1/sqrt(128)*log2(e).
#define QK_PRE 0.12751743f
__global__ __launch_bounds__(256) void rms_rope(
    const float* __restrict__ qkv, const float* __restrict__ qg,
    const float* __restrict__ kg, u16* __restrict__ qb,
    u16* __restrict__ kb) {
  const int gw   = blockIdx.x * 4 + (threadIdx.x >> 6);
  const int lane = threadIdx.x & 63;
  const int row  = gw / 20;            // 0..4095
  const int slot = gw % 20;            // 0..15 q, 16..19 k
  const int b = row >> 11, pos = row & 2047;

  int colbase = (slot < 16) ? slot * 128 : 2048 + (slot - 16) * 128;
  const float* src = qkv + (size_t)row * NQKV + colbase;
  float2 v = *(const float2*)(src + 2 * lane);
  float re = v.x, im = v.y;

  float ss = re * re + im * im;
#pragma unroll
  for (int m = 1; m < 64; m <<= 1) ss += __shfl_xor(ss, m, 64);
  float inv = rsqrtf(ss * (1.0f / 128.0f) + 1e-6f);
  const float* gamma = (slot < 16) ? qg : kg;
  re = re * inv * gamma[2 * lane];
  im = im * inv * gamma[2 * lane + 1];
  // rope: freq = 10000^(-lane/64) = 2^(-lane*log2(1e4)/64)
  float freq = fexp2(-(float)lane * (13.287712379549449f / 64.0f));
  float ang = (float)pos * freq;
  float s, c;
  sincosf(ang, &s, &c);
  float ore = re * c - im * s;
  float oim = re * s + im * c;
  if (slot < 16) { ore *= QK_PRE; oim *= QK_PRE; }

  ushort2 o; o.x = f2bf(ore); o.y = f2bf(oim);
  u16* dst = (slot < 16)
      ? qb + ((size_t)((b * NHEADS + slot) * L_SEQ) + pos) * HDIM + 2 * lane
      : kb + ((size_t)((b * NKVH + slot - 16) * L_SEQ) + pos) * HDIM + 2 * lane;
  *(ushort2*)dst = o;
}

// ---------------------------------------------------------------- V transpose (f32 qkv cols -> bf16 [b][kvh][d][L])
__global__ __launch_bounds__(256) void transpose_v(
    const float* __restrict__ qkv, u16* __restrict__ vt) {
  __shared__ u16 Ls[64][68];
  const int pt = blockIdx.x;     // pos tile (64)
  const int dt = blockIdx.y;     // 64 v-cols per tile (8 tiles over 512)
  const int b  = blockIdx.z;
  const int t  = threadIdx.x;
  {
    int r0 = t >> 4;             // 0..15
    int c4 = (t & 15) << 2;      // 0..60
#pragma unroll
    for (int i = 0; i < 4; ++i) {
      int row = i * 16 + r0;
      float4 v = *(const float4*)(qkv + (size_t)(b * 2048 + pt * 64 + row) * NQKV
                                  + 2560 + dt * 64 + c4);
      Ls[row][c4 + 0] = f2bf(v.x); Ls[row][c4 + 1] = f2bf(v.y);
      Ls[row][c4 + 2] = f2bf(v.z); Ls[row][c4 + 3] = f2bf(v.w);
    }
  }
  __syncthreads();
#pragma unroll
  for (int it = 0; it < 2; ++it) {
    int slot = it * 256 + t;
    int dr = slot >> 3, ch = slot & 7;
    u16x8 o;
#pragma unroll
    for (int j = 0; j < 8; ++j) o[j] = Ls[ch * 8 + j][dr];
    int vc = dt * 64 + dr;       // 0..511
    int kvh = vc >> 7, dd = vc & 127;
    *(u16x8*)(vt + ((size_t)(b * NKVH + kvh) * HDIM + dd) * L_SEQ + pt * 64 + ch * 8) = o;
  }
}

// ---------------------------------------------------------------- flash attention (8-wave 32x32 swapped)
// Block: 512 thr = 8 waves, each wave owns 32 q-rows (block: 256). KVBLK=64, D=128.
// S^T = mfma(K,Q): lane column = q. O^T = mfma(V^T,P^T): lane column = q.
__global__ __launch_bounds__(512) void attn_kernel(
    const u16* __restrict__ qb, const u16* __restrict__ kb,
    const u16* __restrict__ vt, const int* __restrict__ mask,
    u16* __restrict__ ob) {
  __shared__ u16 Ks[2][64 * 128];   // [k][d] rows 256B, chunk-swizzled c^=(k&7)
  __shared__ u16 Vs[2][128 * 64];   // [d][k] rows 128B, chunk-swizzled c^=(d&7)

  const int tid = threadIdx.x;
  const int lane = tid & 63, wid = tid >> 6;
  const int l31 = lane & 31, hi = lane >> 5;
  const int qt = blockIdx.x;        // 8 q-tiles of 256
  const int bh = blockIdx.y;        // b*16 + h
  const int b = bh >> 4, h = bh & 15, kvh = h >> 2;

  const u16* Q  = qb + ((size_t)((b * NHEADS + h) * L_SEQ) + qt * 256 + wid * 32) * HDIM;
  const u16* Kg = kb + (size_t)((b * NKVH + kvh) * L_SEQ) * HDIM;
  const u16* Vg = vt + (size_t)((b * NKVH + kvh) * HDIM) * L_SEQ;  // [128][2048]
  const int* msk = mask + b * L_SEQ;

  // Q frags: lane (q=l31,hi) holds Q[q][ds*16 + hi*8 + 0..7], ds=0..7
  bf16x8 qf[8];
  {
    const u16* qrow = Q + l31 * HDIM + hi * 8;
#pragma unroll
    for (int ds = 0; ds < 8; ++ds) qf[ds] = *(const bf16x8*)(qrow + ds * 16);
  }

  f32x16 o[4] = {};                 // o[db]: O^T[d=db*32+rowmap][q=l31]
  float m_run = -1e30f, l_run = 0.f;

#define STAGE(buf, tt)                                                          \
  {                                                                             \
    const int kv0 = (tt) * 64;                                                  \
    _Pragma("unroll")                                                           \
    for (int it = 0; it < 2; ++it) {                                            \
      int cc = it * 512 + tid;                                                  \
      int kr = cc >> 4, cs = cc & 15;                                           \
      GLOAD_LDS16(Kg + (size_t)(kv0 + kr) * HDIM + ((cs ^ (kr & 7)) << 3),      \
                  &Ks[buf][(it * 512 + wid * 64) * 8]);                         \
    }                                                                           \
    _Pragma("unroll")                                                           \
    for (int it = 0; it < 2; ++it) {                                            \
      int cc = it * 512 + tid;                                                  \
      int dr = cc >> 3, cs = cc & 7;                                            \
      GLOAD_LDS16(Vg + (size_t)dr * L_SEQ + kv0 + ((cs ^ (dr & 7)) << 3),       \
                  &Vs[buf][(it * 512 + wid * 64) * 8]);                         \
    }                                                                           \
  }

  STAGE(0, 0);
  __syncthreads();

  const int NT = L_SEQ / 64;        // 32
  for (int t = 0; t < NT; ++t) {
    const int cur = t & 1;
    if (t + 1 < NT) STAGE(cur ^ 1, t + 1);

    // ---- S^T = K Q^T  (two 32-k subtiles)
    f32x16 st[2] = {};
#pragma unroll
    for (int s = 0; s < 2; ++s) {
      const int r = s * 32 + l31;
      const int rsw = r & 7;
#pragma unroll
      for (int ds = 0; ds < 8; ++ds) {
        bf16x8 kf = *(const bf16x8*)&Ks[cur][r * 128 + (((ds * 2 + hi) ^ rsw) << 3)];
        st[s] = __builtin_amdgcn_mfma_f32_32x32x16_bf16(kf, qf[ds], st[s], 0, 0, 0);
      }
    }

    // ---- mask (fast path: all ones)
    int mk = msk[t * 64 + lane];
    if (!__all(mk != 0)) {
#pragma unroll
      for (int s = 0; s < 2; ++s)
#pragma unroll
        for (int r = 0; r < 16; ++r) {
          int k = t * 64 + s * 32 + (r & 3) + 8 * (r >> 2) + 4 * hi;
          if (msk[k] == 0) st[s][r] = -1e30f;
        }
    }

    // ---- online softmax (log2 domain; q pre-scaled by 1/sqrt(d)*log2e)
    float mx = st[0][0];
#pragma unroll
    for (int s = 0; s < 2; ++s)
#pragma unroll
      for (int r = 0; r < 16; ++r) mx = fmaxf(mx, st[s][r]);
    mx = fmaxf(mx, __shfl_xor(mx, 32, 64));

    // defer-max: rescale only when tile max exceeds running max by >11
    if (!__all(mx <= m_run + 11.0f)) {
      float mn = fmaxf(m_run, mx);
      float alpha = fexp2(m_run - mn);
      m_run = mn;
      l_run *= alpha;
#pragma unroll
      for (int db = 0; db < 4; ++db)
#pragma unroll
        for (int r = 0; r < 16; ++r) o[db][r] *= alpha;
    }

    float psum = 0.f;
#pragma unroll
    for (int s = 0; s < 2; ++s)
#pragma unroll
      for (int r = 0; r < 16; ++r) {
        float p = fexp2(st[s][r] - m_run);
        psum += p;
        st[s][r] = p;
      }
    psum += __shfl_xor(psum, 32, 64);
    l_run += psum;

    // ---- pack P -> bf16 frags via cvt_pk + permlane32_swap (T12)
    // frag(ks): lane holds P[q=l31][ks*16 + hi*8 + j], j=0..7
    bf16x8 pfrag[4];
#pragma unroll
    for (int s = 0; s < 2; ++s) {
      uint32_t Ap[4], Bp[4];
#pragma unroll
      for (int g = 0; g < 4; ++g) {
        Ap[g] = cvtpk(st[s][4 * g + 0], st[s][4 * g + 1]);
        Bp[g] = cvtpk(st[s][4 * g + 2], st[s][4 * g + 3]);
      }
#pragma unroll
      for (int kq = 0; kq < 2; ++kq) {
        uint32_t x0 = Ap[2 * kq], y0 = Ap[2 * kq + 1]; plswap(x0, y0);
        uint32_t x1 = Bp[2 * kq], y1 = Bp[2 * kq + 1]; plswap(x1, y1);
        union { uint32_t w[4]; bf16x8 v; } u;
        u.w[0] = x0; u.w[1] = x1; u.w[2] = y0; u.w[3] = y1;
        pfrag[s * 2 + kq] = u.v;
      }
    }

    // ---- O^T += V^T P^T
#pragma unroll
    for (int ks = 0; ks < 4; ++ks) {
#pragma unroll
      for (int db = 0; db < 4; ++db) {
        const int dr = db * 32 + l31;
        bf16x8 vf = *(const bf16x8*)&Vs[cur][dr * 64 + (((ks * 2 + hi) ^ (dr & 7)) << 3)];
        o[db] = __builtin_amdgcn_mfma_f32_32x32x16_bf16(vf, pfrag[ks], o[db], 0, 0, 0);
      }
    }

    __syncthreads();
  }

  // ---- epilogue: normalize, write O[q][h*128+d] (q = lane column, per-lane scalar)
  float inv = 1.0f / l_run;
  u16* orow = ob + (size_t)(b * L_SEQ + qt * 256 + wid * 32 + l31) * DIMN + h * HDIM;
#pragma unroll
  for (int db = 0; db < 4; ++db)
#pragma unroll
    for (int r = 0; r < 16; r += 2) {
      int d = db * 32 + (r & 3) + 8 * (r >> 2) + 4 * hi;
      ushort2 o2;
      o2.x = f2bf(o[db][r] * inv);
      o2.y = f2bf(o[db][r + 1] * inv);
      *(ushort2*)(orow + d) = o2;
    }
}

// ---------------------------------------------------------------- launch
extern "C" void kernel_launch(void* const* d_in, const int* in_sizes, int n_in,
                              void* d_out, int out_size, void* d_ws, size_t ws_size,
                              hipStream_t stream) {
  const float* x  = (const float*)d_in[0];
  const int* mask = (const int*)d_in[1];
  const float* Wq = (const float*)d_in[2];
  const float* Wk = (const float*)d_in[3];
  const float* Wv = (const float*)d_in[4];
  const float* Wo = (const float*)d_in[5];
  const float* qg = (const float*)d_in[6];
  const float* kg = (const float*)d_in[7];
  float* out = (float*)d_out;

  // workspace layout (bytes): total 113,246,208
  char* ws = (char*)d_ws;
  u16*   xb   = (u16*)(ws + 0);           // 16 MB   [4096,2048] bf16
  u16*   wqkv = (u16*)(ws + 16777216);    // 12 MB   [3072,2048] bf16
  u16*   wob  = (u16*)(ws + 29360128);    //  8 MB   [2048,2048] bf16
  float* qkv  = (float*)(ws + 37748736);  // 48 MB   [4096,3072] f32
  u16*   qb   = (u16*)(ws + 88080384);    // 16 MB   [B,H,L,HD] bf16 (pre-scaled)
  u16*   kb   = (u16*)(ws + 104857600);   //  4 MB   [B,KVH,L,HD]
  u16*   vtb  = (u16*)(ws + 109051904);   //  4 MB   [B,KVH,HD,L] (transposed V)
  u16*   ob   = (u16*)(ws + 37748736);    // 16 MB, aliases qkv (free after rms_rope+transpose_v)

  conv_f32_bf16<<<1024, 256, 0, stream>>>(x,  xb,   2097152);
  conv_f32_bf16<<<1024, 256, 0, stream>>>(Wq, wqkv, 1048576);
  conv_f32_bf16<<<512,  256, 0, stream>>>(Wk, wqkv + 4194304, 262144);
  conv_f32_bf16<<<512,  256, 0, stream>>>(Wv, wqkv + 5242880, 262144);
  conv_f32_bf16<<<1024, 256, 0, stream>>>(Wo, wob,  1048576);

  gemm_bf16_bt<<<dim3(NQKV / 128, MROWS / 128), 256, 0, stream>>>(
      xb, wqkv, qkv, MROWS, NQKV, DIMN);
  rms_rope<<<MROWS * 20 / 4, 256, 0, stream>>>(qkv, qg, kg, qb, kb);
  transpose_v<<<dim3(32, 8, 2), 256, 0, stream>>>(qkv, vtb);
  attn_kernel<<<dim3(L_SEQ / 256, BATCH * NHEADS), 512, 0, stream>>>(
      qb, kb, vtb, mask, ob);
  gemm_bf16_bt<<<dim3(DIMN / 128, MROWS / 128), 256, 0, stream>>>(
      ob, wob, out, MROWS, DIMN, DIMN);
}

// Round 9
// 366.291 us; speedup vs baseline: 1.3841x; 1.0170x over previous
//
#include <hip/hip_runtime.h>
#include <hip/hip_bf16.h>
#include <stdint.h>

// Problem constants
#define DIMN   2048
#define L_SEQ  2048
#define BATCH  2
#define NHEADS 16
#define NKVH   4
#define HDIM   128
#define MROWS  (BATCH * L_SEQ)          // 4096
#define NQKV   (DIMN + 2 * NKVH * HDIM) // 3072

typedef unsigned short u16;
typedef __bf16 bf16_t;
typedef bf16_t bf16x8 __attribute__((ext_vector_type(8)));
typedef float  f32x4  __attribute__((ext_vector_type(4)));
typedef float  f32x16 __attribute__((ext_vector_type(16)));
typedef u16    u16x8  __attribute__((ext_vector_type(8)));

__device__ __forceinline__ u16 f2bf(float f) {
  union { float f; uint32_t u; } v; v.f = f;
  uint32_t r = v.u + 0x7fffu + ((v.u >> 16) & 1u);   // RNE
  return (u16)(r >> 16);
}

// 2^x via v_exp_f32 (log2-domain softmax)
__device__ __forceinline__ float fexp2(float x) {
  float r; asm("v_exp_f32 %0, %1" : "=v"(r) : "v"(x)); return r;
}
// pack 2 f32 -> 1 u32 of 2 bf16 (lo=a, hi=b), RNE
__device__ __forceinline__ uint32_t cvtpk(float a, float b) {
  uint32_t r; asm("v_cvt_pk_bf16_f32 %0, %1, %2" : "=v"(r) : "v"(a), "v"(b)); return r;
}
// v_permlane32_swap_b32: a'[l>=32]=b[l-32], b'[l<32]=a[l+32]
__device__ __forceinline__ void plswap(uint32_t& a, uint32_t& b) {
  asm volatile("v_permlane32_swap_b32 %0, %1" : "+v"(a), "+v"(b));
}

// async global->LDS, 16B per lane; LDS dest = wave-uniform base + lane*16
#define GLOAD_LDS16(gp, lp)                                                     \
  __builtin_amdgcn_global_load_lds(                                             \
      (const __attribute__((address_space(1))) void*)(gp),                      \
      (__attribute__((address_space(3))) void*)(lp), 16, 0, 0)

#define BARR   __builtin_amdgcn_s_barrier()
#define SCHED0 __builtin_amdgcn_sched_barrier(0)
#define LGKM0  asm volatile("s_waitcnt lgkmcnt(0)" ::: "memory")
#define VMC4   asm volatile("s_waitcnt vmcnt(4)" ::: "memory")
#define VMC0   asm volatile("s_waitcnt vmcnt(0)" ::: "memory")

// ---------------------------------------------------------------- convert
__global__ void conv_f32_bf16(const float* __restrict__ src,
                              u16* __restrict__ dst, int n4) {
  int i = blockIdx.x * blockDim.x + threadIdx.x;
  int stride = gridDim.x * blockDim.x;
  for (; i < n4; i += stride) {
    float4 v = ((const float4*)src)[i];
    ushort4 o;
    o.x = f2bf(v.x); o.y = f2bf(v.y); o.z = f2bf(v.z); o.w = f2bf(v.w);
    ((ushort4*)dst)[i] = o;
  }
}

// ---------------------------------------------------------------- GEMM 256x256, BK=64, 8-phase
// C[M,N] f32 rm = A[M,K] bf16 rm * B[N,K]^T bf16 rm.  8 waves (2M x 4N), per-wave 128x64.
// LDS: 8 slots x 16KB (unit = [256 rows][32 k] of A or B).  Unit h: tile=h>>2,
// u=h&3 (0=A-k0,1=B-k0,2=A-k1,3=B-k1), slot=h&7.  Stage lead L=6 (race-free: the
// overwritten slot's last read is >=1 phase earlier; 2 barriers/phase enforce it).
// Counted vmcnt(4) per K-tile boundary (never 0 until the final tile).
// Read swizzle: chunk ^= (row ^ (row>>2)) & 3 ; staged source pre-swizzled (involution).
__global__ __launch_bounds__(512, 2) void gemm256(
    const u16* __restrict__ A, const u16* __restrict__ B,
    float* __restrict__ C, int M, int N, int K) {
  extern __shared__ u16 lds[];          // 131072 B = 8 slots x 8192 u16
  const int tid = threadIdx.x;
  const int lane = tid & 63, wid = tid >> 6;
  const int l15 = lane & 15, l4 = lane >> 4;
  const int wm = wid >> 2, wn = wid & 3;
  const int bm = blockIdx.y, bn = blockIdx.x;
  const int rbA = bm * 256, rbB = bn * 256;
  const int NKT = K >> 6;
  const int swz = l4 ^ ((l15 ^ (l15 >> 2)) & 3);   // row&15 == l15 for all frag rows

  f32x4 acc[8][4] = {};

#define STAGE_U(h_)                                                            \
  if ((h_) < 4 * NKT) {                                                        \
    const int u_ = (h_) & 3;                                                   \
    const u16* sp_ = (u_ & 1) ? B : A;                                         \
    const int rb_ = (u_ & 1) ? rbB : rbA;                                      \
    const int k0_ = (((h_) >> 2) << 6) + ((u_ >> 1) << 5);                     \
    u16* dp_ = lds + (((h_) & 7) << 13) + (wid << 9);                          \
    _Pragma("unroll")                                                          \
    for (int i_ = 0; i_ < 2; ++i_) {                                           \
      int cc_ = i_ * 512 + tid;                                                \
      int r_ = cc_ >> 2;                                                       \
      GLOAD_LDS16(sp_ + (size_t)(rb_ + r_) * K + k0_ +                         \
                      (((cc_ & 3) ^ ((r_ ^ (r_ >> 2)) & 3)) << 3),             \
                  dp_ + i_ * 4096);                                            \
    }                                                                          \
  }

#define RD_A(dst, sA, rowbase)                                                 \
  _Pragma("unroll")                                                            \
  for (int mf_ = 0; mf_ < 4; ++mf_)                                            \
    dst[mf_] = *(const bf16x8*)&lds[((sA) << 13) +                             \
        ((rowbase) + mf_ * 16 + l15) * 32 + (swz << 3)];

#define RD_B(dst, sB)                                                          \
  _Pragma("unroll")                                                            \
  for (int nf_ = 0; nf_ < 4; ++nf_)                                            \
    dst[nf_] = *(const bf16x8*)&lds[((sB) << 13) +                             \
        (wn * 64 + nf_ * 16 + l15) * 32 + (swz << 3)];

#define MM(jj, aa, bb)                                                         \
  __builtin_amdgcn_s_setprio(1);                                               \
  _Pragma("unroll")                                                            \
  for (int mf_ = 0; mf_ < 4; ++mf_)                                            \
    _Pragma("unroll")                                                          \
    for (int nf_ = 0; nf_ < 4; ++nf_)                                          \
      acc[(jj) * 4 + mf_][nf_] = __builtin_amdgcn_mfma_f32_16x16x32_bf16(      \
          aa[mf_], bb[nf_], acc[(jj) * 4 + mf_][nf_], 0, 0, 0);                \
  __builtin_amdgcn_s_setprio(0);

  // prologue: units 0..5 (tile 0 complete + A-k0,B-k0 of tile 1)
#pragma unroll
  for (int h = 0; h < 6; ++h) { STAGE_U(h); }
  VMC4;          // tile 0 (units 0..3) landed
  BARR; SCHED0;

  for (int c = 0; c < NKT; ++c) {
    const int cb = (c & 1) << 2;
    const int p0 = c << 2;
    bf16x8 a[4], b[4];
    // ---- sub 0: j=0, kk=0  (8 ds_reads)
    RD_A(a, cb + 0, wm * 128);
    RD_B(b, cb + 1);
    STAGE_U(p0 + 6);
    BARR; LGKM0; SCHED0;
    MM(0, a, b);
    BARR; SCHED0;
    // ---- sub 1: j=1, kk=0  (B cached in regs)
    RD_A(a, cb + 0, wm * 128 + 64);
    STAGE_U(p0 + 7);
    BARR; LGKM0; SCHED0;
    MM(1, a, b);
    BARR; SCHED0;
    // ---- sub 2: j=0, kk=1
    RD_A(a, cb + 2, wm * 128);
    RD_B(b, cb + 3);
    STAGE_U(p0 + 8);
    BARR; LGKM0; SCHED0;
    MM(0, a, b);
    BARR; SCHED0;
    // ---- sub 3: j=1, kk=1
    RD_A(a, cb + 2, wm * 128 + 64);
    STAGE_U(p0 + 9);
    BARR; LGKM0; SCHED0;
    MM(1, a, b);
    if (c == NKT - 2) { VMC0; } else if (c < NKT - 2) { VMC4; }
    BARR; SCHED0;
  }

  // epilogue: C/D layout col=lane&15, row=(lane>>4)*4+j
  const int crow0 = bm * 256 + wm * 128;
  const int ccol0 = bn * 256 + wn * 64;
#pragma unroll
  for (int mf = 0; mf < 8; ++mf)
#pragma unroll
    for (int nf = 0; nf < 4; ++nf)
#pragma unroll
      for (int j = 0; j < 4; ++j)
        C[(size_t)(crow0 + mf * 16 + l4 * 4 + j) * N + ccol0 + nf * 16 + l15] =
            acc[mf][nf][j];
#undef STAGE_U
#undef RD_A
#undef RD_B
#undef MM
}

// ---------------------------------------------------------------- RMSNorm + RoPE (q,k only)
// qkv rows: [0..2048) q (16 heads x128), [2048..2560) k. q prescaled by 1/sqrt(128)*log2(e).
#define QK_PRE 0.12751743f
__global__ __launch_bounds__(256) void rms_rope(
    const float* __restrict__ qkv, const float* __restrict__ qg,
    const float* __restrict__ kg, u16* __restrict__ qb,
    u16* __restrict__ kb) {
  const int gw   = blockIdx.x * 4 + (threadIdx.x >> 6);
  const int lane = threadIdx.x & 63;
  const int row  = gw / 20;            // 0..4095
  const int slot = gw % 20;            // 0..15 q, 16..19 k
  const int b = row >> 11, pos = row & 2047;

  int colbase = (slot < 16) ? slot * 128 : 2048 + (slot - 16) * 128;
  const float* src = qkv + (size_t)row * NQKV + colbase;
  float2 v = *(const float2*)(src + 2 * lane);
  float re = v.x, im = v.y;

  float ss = re * re + im * im;
#pragma unroll
  for (int m = 1; m < 64; m <<= 1) ss += __shfl_xor(ss, m, 64);
  float inv = rsqrtf(ss * (1.0f / 128.0f) + 1e-6f);
  const float* gamma = (slot < 16) ? qg : kg;
  re = re * inv * gamma[2 * lane];
  im = im * inv * gamma[2 * lane + 1];
  // rope: freq = 10000^(-lane/64) = 2^(-lane*log2(1e4)/64)
  float freq = fexp2(-(float)lane * (13.287712379549449f / 64.0f));
  float ang = (float)pos * freq;
  float s, c;
  sincosf(ang, &s, &c);
  float ore = re * c - im * s;
  float oim = re * s + im * c;
  if (slot < 16) { ore *= QK_PRE; oim *= QK_PRE; }

  ushort2 o; o.x = f2bf(ore); o.y = f2bf(oim);
  u16* dst = (slot < 16)
      ? qb + ((size_t)((b * NHEADS + slot) * L_SEQ) + pos) * HDIM + 2 * lane
      : kb + ((size_t)((b * NKVH + slot - 16) * L_SEQ) + pos) * HDIM + 2 * lane;
  *(ushort2*)dst = o;
}

// ---------------------------------------------------------------- V transpose (f32 qkv cols -> bf16 [b][kvh][d][L])
__global__ __launch_bounds__(256) void transpose_v(
    const float* __restrict__ qkv, u16* __restrict__ vt) {
  __shared__ u16 Ls[64][68];
  const int pt = blockIdx.x;     // pos tile (64)
  const int dt = blockIdx.y;     // 64 v-cols per tile (8 tiles over 512)
  const int b  = blockIdx.z;
  const int t  = threadIdx.x;
  {
    int r0 = t >> 4;             // 0..15
    int c4 = (t & 15) << 2;      // 0..60
#pragma unroll
    for (int i = 0; i < 4; ++i) {
      int row = i * 16 + r0;
      float4 v = *(const float4*)(qkv + (size_t)(b * 2048 + pt * 64 + row) * NQKV
                                  + 2560 + dt * 64 + c4);
      Ls[row][c4 + 0] = f2bf(v.x); Ls[row][c4 + 1] = f2bf(v.y);
      Ls[row][c4 + 2] = f2bf(v.z); Ls[row][c4 + 3] = f2bf(v.w);
    }
  }
  __syncthreads();
#pragma unroll
  for (int it = 0; it < 2; ++it) {
    int slot = it * 256 + t;
    int dr = slot >> 3, ch = slot & 7;
    u16x8 o;
#pragma unroll
    for (int j = 0; j < 8; ++j) o[j] = Ls[ch * 8 + j][dr];
    int vc = dt * 64 + dr;       // 0..511
    int kvh = vc >> 7, dd = vc & 127;
    *(u16x8*)(vt + ((size_t)(b * NKVH + kvh) * HDIM + dd) * L_SEQ + pt * 64 + ch * 8) = o;
  }
}

// ---------------------------------------------------------------- flash attention (8-wave 32x32 swapped)
__global__ __launch_bounds__(512) void attn_kernel(
    const u16* __restrict__ qb, const u16* __restrict__ kb,
    const u16* __restrict__ vt, const int* __restrict__ mask,
    u16* __restrict__ ob) {
  __shared__ u16 Ks[2][64 * 128];   // [k][d] rows 256B, chunk-swizzled c^=(k&7)
  __shared__ u16 Vs[2][128 * 64];   // [d][k] rows 128B, chunk-swizzled c^=(d&7)

  const int tid = threadIdx.x;
  const int lane = tid & 63, wid = tid >> 6;
  const int l31 = lane & 31, hi = lane >> 5;
  const int qt = blockIdx.x;        // 8 q-tiles of 256
  const int bh = blockIdx.y;        // b*16 + h
  const int b = bh >> 4, h = bh & 15, kvh = h >> 2;

  const u16* Q  = qb + ((size_t)((b * NHEADS + h) * L_SEQ) + qt * 256 + wid * 32) * HDIM;
  const u16* Kg = kb + (size_t)((b * NKVH + kvh) * L_SEQ) * HDIM;
  const u16* Vg = vt + (size_t)((b * NKVH + kvh) * HDIM) * L_SEQ;  // [128][2048]
  const int* msk = mask + b * L_SEQ;

  bf16x8 qf[8];
  {
    const u16* qrow = Q + l31 * HDIM + hi * 8;
#pragma unroll
    for (int ds = 0; ds < 8; ++ds) qf[ds] = *(const bf16x8*)(qrow + ds * 16);
  }

  f32x16 o[4] = {};                 // o[db]: O^T[d=db*32+rowmap][q=l31]
  float m_run = -1e30f, l_run = 0.f;

#define STAGE(buf, tt)                                                          \
  {                                                                             \
    const int kv0 = (tt) * 64;                                                  \
    _Pragma("unroll")                                                           \
    for (int it = 0; it < 2; ++it) {                                            \
      int cc = it * 512 + tid;                                                  \
      int kr = cc >> 4, cs = cc & 15;                                           \
      GLOAD_LDS16(Kg + (size_t)(kv0 + kr) * HDIM + ((cs ^ (kr & 7)) << 3),      \
                  &Ks[buf][(it * 512 + wid * 64) * 8]);                         \
    }                                                                           \
    _Pragma("unroll")                                                           \
    for (int it = 0; it < 2; ++it) {                                            \
      int cc = it * 512 + tid;                                                  \
      int dr = cc >> 3, cs = cc & 7;                                            \
      GLOAD_LDS16(Vg + (size_t)dr * L_SEQ + kv0 + ((cs ^ (dr & 7)) << 3),       \
                  &Vs[buf][(it * 512 + wid * 64) * 8]);                         \
    }                                                                           \
  }

  STAGE(0, 0);
  __syncthreads();

  const int NT = L_SEQ / 64;        // 32
  for (int t = 0; t < NT; ++t) {
    const int cur = t & 1;
    if (t + 1 < NT) STAGE(cur ^ 1, t + 1);

    // ---- S^T = K Q^T  (two 32-k subtiles)
    f32x16 st[2] = {};
#pragma unroll
    for (int s = 0; s < 2; ++s) {
      const int r = s * 32 + l31;
      const int rsw = r & 7;
#pragma unroll
      for (int ds = 0; ds < 8; ++ds) {
        bf16x8 kf = *(const bf16x8*)&Ks[cur][r * 128 + (((ds * 2 + hi) ^ rsw) << 3)];
        st[s] = __builtin_amdgcn_mfma_f32_32x32x16_bf16(kf, qf[ds], st[s], 0, 0, 0);
      }
    }

    // ---- mask (fast path: all ones)
    int mk = msk[t * 64 + lane];
    if (!__all(mk != 0)) {
#pragma unroll
      for (int s = 0; s < 2; ++s)
#pragma unroll
        for (int r = 0; r < 16; ++r) {
          int k = t * 64 + s * 32 + (r & 3) + 8 * (r >> 2) + 4 * hi;
          if (msk[k] == 0) st[s][r] = -1e30f;
        }
    }

    // ---- online softmax (log2 domain; q pre-scaled by 1/sqrt(d)*log2e)
    float mx = st[0][0];
#pragma unroll
    for (int s = 0; s < 2; ++s)
#pragma unroll
      for (int r = 0; r < 16; ++r) mx = fmaxf(mx, st[s][r]);
    mx = fmaxf(mx, __shfl_xor(mx, 32, 64));

    // defer-max: rescale only when tile max exceeds running max by >11
    if (!__all(mx <= m_run + 11.0f)) {
      float mn = fmaxf(m_run, mx);
      float alpha = fexp2(m_run - mn);
      m_run = mn;
      l_run *= alpha;
#pragma unroll
      for (int db = 0; db < 4; ++db)
#pragma unroll
        for (int r = 0; r < 16; ++r) o[db][r] *= alpha;
    }

    float psum = 0.f;
#pragma unroll
    for (int s = 0; s < 2; ++s)
#pragma unroll
      for (int r = 0; r < 16; ++r) {
        float p = fexp2(st[s][r] - m_run);
        psum += p;
        st[s][r] = p;
      }
    psum += __shfl_xor(psum, 32, 64);
    l_run += psum;

    // ---- pack P -> bf16 frags via cvt_pk + permlane32_swap (T12)
    bf16x8 pfrag[4];
#pragma unroll
    for (int s = 0; s < 2; ++s) {
      uint32_t Ap[4], Bp[4];
#pragma unroll
      for (int g = 0; g < 4; ++g) {
        Ap[g] = cvtpk(st[s][4 * g + 0], st[s][4 * g + 1]);
        Bp[g] = cvtpk(st[s][4 * g + 2], st[s][4 * g + 3]);
      }
#pragma unroll
      for (int kq = 0; kq < 2; ++kq) {
        uint32_t x0 = Ap[2 * kq], y0 = Ap[2 * kq + 1]; plswap(x0, y0);
        uint32_t x1 = Bp[2 * kq], y1 = Bp[2 * kq + 1]; plswap(x1, y1);
        union { uint32_t w[4]; bf16x8 v; } u;
        u.w[0] = x0; u.w[1] = x1; u.w[2] = y0; u.w[3] = y1;
        pfrag[s * 2 + kq] = u.v;
      }
    }

    // ---- O^T += V^T P^T
#pragma unroll
    for (int ks = 0; ks < 4; ++ks) {
#pragma unroll
      for (int db = 0; db < 4; ++db) {
        const int dr = db * 32 + l31;
        bf16x8 vf = *(const bf16x8*)&Vs[cur][dr * 64 + (((ks * 2 + hi) ^ (dr & 7)) << 3)];
        o[db] = __builtin_amdgcn_mfma_f32_32x32x16_bf16(vf, pfrag[ks], o[db], 0, 0, 0);
      }
    }

    __syncthreads();
  }

  // ---- epilogue: normalize, write O[q][h*128+d]
  float inv = 1.0f / l_run;
  u16* orow = ob + (size_t)(b * L_SEQ + qt * 256 + wid * 32 + l31) * DIMN + h * HDIM;
#pragma unroll
  for (int db = 0; db < 4; ++db)
#pragma unroll
    for (int r = 0; r < 16; r += 2) {
      int d = db * 32 + (r & 3) + 8 * (r >> 2) + 4 * hi;
      ushort2 o2;
      o2.x = f2bf(o[db][r] * inv);
      o2.y = f2bf(o[db][r + 1] * inv);
      *(ushort2*)(orow + d) = o2;
    }
}

// ---------------------------------------------------------------- launch
extern "C" void kernel_launch(void* const* d_in, const int* in_sizes, int n_in,
                              void* d_out, int out_size, void* d_ws, size_t ws_size,
                              hipStream_t stream) {
  const float* x  = (const float*)d_in[0];
  const int* mask = (const int*)d_in[1];
  const float* Wq = (const float*)d_in[2];
  const float* Wk = (const float*)d_in[3];
  const float* Wv = (const float*)d_in[4];
  const float* Wo = (const float*)d_in[5];
  const float* qg = (const float*)d_in[6];
  const float* kg = (const float*)d_in[7];
  float* out = (float*)d_out;

  // allow 128 KiB dynamic LDS for gemm256 (idempotent, same work every call)
  hipFuncSetAttribute((const void*)gemm256,
                      hipFuncAttributeMaxDynamicSharedMemorySize, 131072);

  // workspace layout (bytes): total 113,246,208
  char* ws = (char*)d_ws;
  u16*   xb   = (u16*)(ws + 0);           // 16 MB   [4096,2048] bf16
  u16*   wqkv = (u16*)(ws + 16777216);    // 12 MB   [3072,2048] bf16
  u16*   wob  = (u16*)(ws + 29360128);    //  8 MB   [2048,2048] bf16
  float* qkv  = (float*)(ws + 37748736);  // 48 MB   [4096,3072] f32
  u16*   qb   = (u16*)(ws + 88080384);    // 16 MB   [B,H,L,HD] bf16 (pre-scaled)
  u16*   kb   = (u16*)(ws + 104857600);   //  4 MB   [B,KVH,L,HD]
  u16*   vtb  = (u16*)(ws + 109051904);   //  4 MB   [B,KVH,HD,L] (transposed V)
  u16*   ob   = (u16*)(ws + 37748736);    // 16 MB, aliases qkv (free after rms_rope+transpose_v)

  conv_f32_bf16<<<1024, 256, 0, stream>>>(x,  xb,   2097152);
  conv_f32_bf16<<<1024, 256, 0, stream>>>(Wq, wqkv, 1048576);
  conv_f32_bf16<<<512,  256, 0, stream>>>(Wk, wqkv + 4194304, 262144);
  conv_f32_bf16<<<512,  256, 0, stream>>>(Wv, wqkv + 5242880, 262144);
  conv_f32_bf16<<<1024, 256, 0, stream>>>(Wo, wob,  1048576);

  gemm256<<<dim3(NQKV / 256, MROWS / 256), 512, 131072, stream>>>(
      xb, wqkv, qkv, MROWS, NQKV, DIMN);
  rms_rope<<<MROWS * 20 / 4, 256, 0, stream>>>(qkv, qg, kg, qb, kb);
  transpose_v<<<dim3(32, 8, 2), 256, 0, stream>>>(qkv, vtb);
  attn_kernel<<<dim3(L_SEQ / 256, BATCH * NHEADS), 512, 0, stream>>>(
      qb, kb, vtb, mask, ob);
  gemm256<<<dim3(DIMN / 256, MROWS / 256), 512, 131072, stream>>>(
      ob, wob, out, MROWS, DIMN, DIMN);
}